// Round 7
// baseline (635.556 us; speedup 1.0000x reference)
//
#include <hip/hip_runtime.h>
#include <hip/hip_bf16.h>
#include <hip/hip_fp16.h>

// Problem constants
#define NB 64
#define NT 256
#define TC 16
#define NL 25
#define NWORDS 16384   // NB*NT
#define DWd 150        // word-LSTM input dim
#define WEd 100
#define WPB 5          // words per k_char block

typedef _Float16 h2_t __attribute__((ext_vector_type(2)));

__device__ __forceinline__ float sigf(float x){ return __fdividef(1.f, 1.f + __expf(-x)); }
__device__ __forceinline__ float tanhf_(float x){
    float ax = fabsf(x);
    float e = __expf(-2.f*ax);                 // e in (0,1], overflow-safe
    float r = (1.f - e) * __fdividef(1.f, 1.f + e);
    return copysignf(r, x);
}

#if __has_builtin(__builtin_amdgcn_fdot2)
__device__ __forceinline__ float fdot2_(h2_t a, h2_t b, float c){
  return __builtin_amdgcn_fdot2(a, b, c, false);
}
#else
__device__ __forceinline__ float fdot2_(h2_t a, h2_t b, float c){
  return c + (float)a.x*(float)b.x + (float)a.y*(float)b.y;
}
#endif

// ---------------- Kernel 0: gxc[(c,d)][col] = cb_d[col] + sum_k char_emb[c][k]*cWih_d[k*100+col]
__global__ void k_gxc(const float* __restrict__ char_emb,
                      const float* __restrict__ cWih_f, const float* __restrict__ cb_f,
                      const float* __restrict__ cWih_b, const float* __restrict__ cb_b,
                      float* __restrict__ gxc){
  int i = blockIdx.x*blockDim.x + threadIdx.x;
  if (i >= 128*2*100) return;
  int col = i % 100; int d = (i/100) & 1; int c = i/200;
  const float* Wih = d ? cWih_b : cWih_f;
  const float* bb  = d ? cb_b  : cb_f;
  float acc = bb[col];
  #pragma unroll
  for (int k=0;k<25;k++) acc += char_emb[c*25+k]*Wih[k*100+col];
  gxc[i] = acc;
}

// ---------------- Kernel 1: char BiLSTM, thread = (word_in_block, gate_col).
__global__ __launch_bounds__(512) void k_char(const int* __restrict__ char_tensor,
   const int* __restrict__ char_lengths,
   const float* __restrict__ cWhh_f, const float* __restrict__ cWhh_b,
   const float* __restrict__ gxc, float* __restrict__ cf){
  __shared__ float h_lds[WPB][28];    // rows padded to 28 (16B-aligned float4 reads)
  __shared__ float act[WPB][100];
  __shared__ int   chars[WPB][TC];
  __shared__ int   lens[WPB];
  int tid = threadIdx.x;
  int d  = blockIdx.x & 1;
  int wb = blockIdx.x >> 1;           // 0..3276
  int w0 = wb*WPB;
  if (tid < WPB*TC){
    int ww = w0 + tid/TC;
    int cw = ww < NWORDS ? ww : NWORDS-1;
    chars[tid/TC][tid%TC] = char_tensor[cw*TC + (tid%TC)];
  }
  if (tid < WPB){
    int ww = w0 + tid;
    lens[tid] = char_lengths[ww < NWORDS ? ww : NWORDS-1];
  }
  int wsub = tid/100;                 // 0..4 for tid<500
  int j    = tid - wsub*100;          // gate col 0..99
  bool gate_thr = tid < WPB*100;
  const float* Wh = d ? cWhh_b : cWhh_f;
  float wcol[25];
  if (gate_thr){
    #pragma unroll
    for (int k=0;k<25;k++) wcol[k] = Wh[k*100 + j];
  }
  if (gate_thr && j < 28) h_lds[wsub][j] = 0.f;
  float c_reg = 0.f, h_last = 0.f;
  __syncthreads();
  int len = gate_thr ? lens[wsub] : 1;
  bool isg = (j >= 50) && (j < 75);
  float g_all[TC];
  if (gate_thr){
    #pragma unroll
    for (int t=0;t<TC;t++){
      int ci = d ? (len-1-t) : t;
      if (ci < 0 || ci >= TC) ci = 0;
      int cidx = chars[wsub][ci];
      g_all[t] = gxc[(size_t)(cidx*2+d)*100 + j];
    }
  }
  for (int t=0;t<TC;t++){
    if (gate_thr){
      float a = g_all[t];
      const float4* h4 = (const float4*)h_lds[wsub];
      #pragma unroll
      for (int kq=0;kq<6;kq++){
        float4 hq = h4[kq];
        a += hq.x*wcol[4*kq] + hq.y*wcol[4*kq+1] + hq.z*wcol[4*kq+2] + hq.w*wcol[4*kq+3];
      }
      a += h_lds[wsub][24]*wcol[24];
      act[wsub][j] = isg ? tanhf_(a) : sigf(a);
    }
    __syncthreads();
    if (gate_thr && j < 25 && t < len){
      float si = act[wsub][j], sf = act[wsub][25+j], sg = act[wsub][50+j], so = act[wsub][75+j];
      c_reg = sf*c_reg + si*sg;
      float hv = so*tanhf_(c_reg);
      h_lds[wsub][j] = hv;
      h_last = hv;
    }
    __syncthreads();
  }
  if (gate_thr && j < 25){
    int w = w0 + wsub;
    if (w < NWORDS) cf[(size_t)w*56 + d*28 + j] = h_last;
  }
}

// ---------------- Kernel 2: x[p][150] = word_emb[tok[p]] ++ cf[recover[p]] (cf stride 56)
__global__ void k_buildx(const int* __restrict__ tok, const int* __restrict__ recover,
                         const float* __restrict__ word_emb, const float* __restrict__ cf,
                         float* __restrict__ x){
  long i = (long)blockIdx.x*blockDim.x + threadIdx.x;
  if (i >= (long)NWORDS*DWd) return;
  int p = (int)(i/DWd); int e = (int)(i - (long)p*DWd);
  float v;
  if (e < WEd) v = word_emb[(long)tok[p]*WEd + e];
  else {
    int cidx = e - WEd;           // 0..49
    int dd = cidx / 25; int uu = cidx - dd*25;
    v = cf[(size_t)recover[p]*56 + dd*28 + uu];
  }
  x[i] = v;
}

// ---------------- Kernel 3: gx[d][p][400] = wb_d + x[p] @ wWih_d (fp32 tiled, M=16384,N=800,K=150)
__global__ __launch_bounds__(256) void k_wih(const float* __restrict__ x,
    const float* __restrict__ Wf, const float* __restrict__ bf,
    const float* __restrict__ Wb, const float* __restrict__ bbias,
    float* __restrict__ gx){
  __shared__ float As[150][36];
  int tid = threadIdx.x;
  int m0 = (blockIdx.x>>2)*32;
  int nt = blockIdx.x & 3;
  int n0 = nt*256;
  for (int i=tid; i<32*150; i+=256){
    int r = i/150; int k = i - r*150;
    As[k][r] = x[(long)(m0+r)*150 + k];
  }
  __syncthreads();
  int tn = tid & 31; int tm = tid >> 5;
  int j0 = n0 + tn*8;
  bool colok = j0 < 800;
  int d = (j0 >= 400) ? 1 : 0;
  const float* W = d ? Wb : Wf;
  int jc = j0 - d*400;
  float acc[4][8];
  #pragma unroll
  for (int mi=0;mi<4;mi++)
    #pragma unroll
    for (int ni=0;ni<8;ni++) acc[mi][ni]=0.f;
  if (colok){
    for (int k=0;k<150;k++){
      float4 b0 = *(const float4*)&W[k*400 + jc];
      float4 b1 = *(const float4*)&W[k*400 + jc + 4];
      float4 a4 = *(const float4*)&As[k][tm*4];
      float av[4] = {a4.x,a4.y,a4.z,a4.w};
      float bv[8] = {b0.x,b0.y,b0.z,b0.w,b1.x,b1.y,b1.z,b1.w};
      #pragma unroll
      for (int mi=0;mi<4;mi++)
        #pragma unroll
        for (int ni=0;ni<8;ni++) acc[mi][ni] += av[mi]*bv[ni];
    }
    const float* bptr = d ? bbias : bf;
    float bias[8];
    #pragma unroll
    for (int ni=0;ni<8;ni++) bias[ni] = bptr[jc+ni];
    #pragma unroll
    for (int mi=0;mi<4;mi++){
      int p = m0 + tm*4 + mi;
      float* orow = gx + ((long)d*NWORDS + p)*400 + jc;
      #pragma unroll
      for (int ni=0;ni<8;ni++) orow[ni] = acc[mi][ni] + bias[ni];
    }
  }
}

// ---------------- Kernel 4: word LSTM recurrence v5.
// block = (seq, dir), 128 threads (2 waves). Thread u<100 owns UNIT u: computes
// all 4 gates i,f,g,o in-thread (no act[] exchange). h stored f16 in LDS ->
// 13 ds_read_b128/thread/step (LDS pipe off the critical path). Weights packed
// half2 in 200 VGPRs (staged global->LDS->convert: conversion defeats remat).
// Inner loop = 200 v_dot2_f32_f16. 2 barriers/step.
__global__ __launch_bounds__(128, 1) void k_wlstm(const float* __restrict__ gx,
     const float* __restrict__ Whf, const float* __restrict__ Whb,
     float* __restrict__ hseq){
  __shared__ float wstage[8000];                 // 20 rows x 400 cols (32KB)
  __shared__ __align__(16) _Float16 h16[112];
  int tid = threadIdx.x;
  int s = blockIdx.x & 63; int d = blockIdx.x >> 6;
  const float* Wh = d ? Whb : Whf;
  bool uthr = tid < 100;
  h2_t wi[50], wf[50], wg[50], wo[50];
  #pragma unroll
  for (int ch=0; ch<5; ch++){                    // rows 20ch .. 20ch+19
    for (int i=tid; i<2000; i+=128)
      ((float4*)wstage)[i] = ((const float4*)(Wh + ch*8000))[i];
    __syncthreads();
    if (uthr){
      #pragma unroll
      for (int p=0;p<10;p++){                    // pair of rows (2p,2p+1)
        int k = ch*10 + p;
        wi[k] = (h2_t){(_Float16)wstage[(2*p)*400 + tid],       (_Float16)wstage[(2*p+1)*400 + tid]};
        wf[k] = (h2_t){(_Float16)wstage[(2*p)*400 + 100 + tid], (_Float16)wstage[(2*p+1)*400 + 100 + tid]};
        wg[k] = (h2_t){(_Float16)wstage[(2*p)*400 + 200 + tid], (_Float16)wstage[(2*p+1)*400 + 200 + tid]};
        wo[k] = (h2_t){(_Float16)wstage[(2*p)*400 + 300 + tid], (_Float16)wstage[(2*p+1)*400 + 300 + tid]};
      }
    }
    __syncthreads();
  }
  if (tid < 112) h16[tid] = (_Float16)0.f;
  float c_reg = 0.f;
  const float* gxd = gx + ((long)d*NWORDS + (long)s*256)*400;
  __syncthreads();
  float gi=0.f, gf=0.f, gg=0.f, go=0.f;
  if (uthr){
    int t0 = d ? 255 : 0;
    gi = gxd[t0*400 + tid];       gf = gxd[t0*400 + 100 + tid];
    gg = gxd[t0*400 + 200 + tid]; go = gxd[t0*400 + 300 + tid];
  }
  for (int t=0;t<256;t++){
    float ai=gi, af=gf, ag=gg, ao=go;
    if (uthr && t+1 < 256){
      int tn = d ? (255-(t+1)) : (t+1);
      gi = gxd[tn*400 + tid];       gf = gxd[tn*400 + 100 + tid];
      gg = gxd[tn*400 + 200 + tid]; go = gxd[tn*400 + 300 + tid];
    }
    if (uthr){
      h2_t hl[52];
      #pragma unroll
      for (int q=0;q<13;q++)
        *(float4*)&hl[4*q] = ((const float4*)h16)[q];
      #pragma unroll
      for (int k=0;k<50;k++){
        h2_t hv = hl[k];
        ai = fdot2_(hv, wi[k], ai);
        af = fdot2_(hv, wf[k], af);
        ag = fdot2_(hv, wg[k], ag);
        ao = fdot2_(hv, wo[k], ao);
      }
    }
    __syncthreads();   // all h16 reads of this step done
    if (uthr){
      c_reg = sigf(af)*c_reg + sigf(ai)*tanhf_(ag);
      float hv = sigf(ao)*tanhf_(c_reg);
      h16[tid] = (_Float16)hv;
      int ttc = d ? (255-t) : t;
      hseq[((long)d*NWORDS + s*256 + ttc)*100 + tid] = hv;
    }
    __syncthreads();   // new h visible
  }
}

// ---------------- Kernel 5: emissions em[p][25] = b_tag + concat(h_f,h_b)[p] @ W_tag
__global__ __launch_bounds__(256) void k_em(const float* __restrict__ hseq,
    const float* __restrict__ Wtag, const float* __restrict__ btag,
    float* __restrict__ em){
  __shared__ float hrow[8][200];
  __shared__ float Ws[5000];
  int tid = threadIdx.x;
  for (int i=tid;i<5000;i+=256) Ws[i] = Wtag[i];
  int p0 = blockIdx.x*8;
  for (int i=tid;i<8*200;i+=256){
    int r = i/200; int k = i - r*200;
    int p = p0+r;
    hrow[r][k] = (k<100) ? hseq[(long)p*100+k] : hseq[((long)NWORDS + p)*100 + (k-100)];
  }
  __syncthreads();
  int r = tid>>5; int c = tid&31;
  if (c<25){
    float acc = btag[c];
    for (int k=0;k<200;k++) acc += hrow[r][k]*Ws[k*25+c];
    em[(long)(p0+r)*25 + c] = acc;
  }
}

// ---------------- Kernel 6: CRF per sequence: part[s] = logZ - gold.
__global__ __launch_bounds__(64) void k_crf(const float* __restrict__ em,
    const int* __restrict__ tag, const float* __restrict__ trans,
    const float* __restrict__ start, const float* __restrict__ endv,
    float* __restrict__ part){
  int s = blockIdx.x;
  int lane = threadIdx.x;
  int j = lane & 31; int kg = lane >> 5;
  int k0 = kg ? 13 : 0; int kcnt = kg ? 12 : 13;
  const float* emb = em + (long)s*256*25;
  float tr[13];
  #pragma unroll
  for (int kk=0;kk<13;kk++){
    int k = k0+kk;
    tr[kk] = (k<25 && j<25) ? trans[k*25+j] : 0.f;
  }
  float alpha = (j<25) ? (start[j] + emb[j]) : -1e30f;
  float enext = (j<25) ? emb[25 + j] : 0.f;
  for (int t=1;t<256;t++){
    float ecur = enext;
    if (t<255 && j<25) enext = emb[(t+1)*25 + j];
    float m = -1e30f;
    #pragma unroll
    for (int kk=0;kk<13;kk++){
      if (kk<kcnt){
        float a = __shfl(alpha, k0+kk, 64);
        m = fmaxf(m, a + tr[kk]);
      }
    }
    m = fmaxf(m, __shfl_xor(m, 32, 64));
    float ssum = 0.f;
    #pragma unroll
    for (int kk=0;kk<13;kk++){
      if (kk<kcnt){
        float a = __shfl(alpha, k0+kk, 64);
        ssum += __expf(a + tr[kk] - m);
      }
    }
    ssum += __shfl_xor(ssum, 32, 64);
    float anew = __logf(ssum) + m + ecur;
    alpha = (j<25) ? anew : -1e30f;
  }
  float val = (j<25 && kg==0) ? (alpha + endv[j]) : -1e30f;
  float m2 = -1e30f;
  for (int k=0;k<25;k++) m2 = fmaxf(m2, __shfl(val, k, 64));
  float s2 = 0.f;
  for (int k=0;k<25;k++) s2 += __expf(__shfl(val, k, 64) - m2);
  float logZ = __logf(s2) + m2;
  const int* tg = tag + s*256;
  float gp = 0.f;
  for (int t=lane; t<256; t+=64){
    int a = tg[t];
    gp += emb[t*25 + a];
    if (t<255) gp += trans[a*25 + tg[t+1]];
  }
  #pragma unroll
  for (int off=32; off; off>>=1) gp += __shfl_xor(gp, off, 64);
  if (lane==0){
    float gold = gp + start[tg[0]] + endv[tg[255]];
    part[s] = logZ - gold;
  }
}

// ---------------- Kernel 7: final reduce
__global__ __launch_bounds__(64) void k_red(const float* __restrict__ part, float* __restrict__ out){
  float v = part[threadIdx.x];
  #pragma unroll
  for (int off=32; off; off>>=1) v += __shfl_xor(v, off, 64);
  if (threadIdx.x==0) out[0] = v;
}

extern "C" void kernel_launch(void* const* d_in, const int* in_sizes, int n_in,
                              void* d_out, int out_size, void* d_ws, size_t ws_size,
                              hipStream_t stream){
  const int* tok          = (const int*)d_in[0];
  const int* tagp         = (const int*)d_in[1];
  const int* char_tensor  = (const int*)d_in[3];
  const int* char_lengths = (const int*)d_in[4];
  const int* recover      = (const int*)d_in[5];
  const float* word_emb = (const float*)d_in[6];
  const float* char_emb = (const float*)d_in[7];
  const float* cWih_f=(const float*)d_in[8];  const float* cWhh_f=(const float*)d_in[9];  const float* cb_f=(const float*)d_in[10];
  const float* cWih_b=(const float*)d_in[11]; const float* cWhh_b=(const float*)d_in[12]; const float* cb_b=(const float*)d_in[13];
  const float* wWih_f=(const float*)d_in[14]; const float* wWhh_f=(const float*)d_in[15]; const float* wb_f=(const float*)d_in[16];
  const float* wWih_b=(const float*)d_in[17]; const float* wWhh_b=(const float*)d_in[18]; const float* wb_b=(const float*)d_in[19];
  const float* W_tag=(const float*)d_in[20];  const float* b_tag=(const float*)d_in[21];
  const float* trans=(const float*)d_in[22];  const float* startv=(const float*)d_in[23]; const float* endv=(const float*)d_in[24];

  float* ws  = (float*)d_ws;
  float* gxc = ws;                 // 25600
  float* cf  = ws + 25600;         // 16384*56 = 917504
  float* x   = ws + 943104;        // 2457600
  float* gx  = ws + 3400704;       // 13107200
  float* hseq= ws + 16507904;      // 3276800
  float* em  = ws + 943104;        // overlays x (dead after k_wih), 409600
  float* part= ws + 19784704;      // 64   (high water ~79.1 MB)
  float* out = (float*)d_out;

  k_gxc   <<<100, 256, 0, stream>>>(char_emb, cWih_f, cb_f, cWih_b, cb_b, gxc);
  k_char  <<<6554,512, 0, stream>>>(char_tensor, char_lengths, cWhh_f, cWhh_b, gxc, cf);
  k_buildx<<<9600,256, 0, stream>>>(tok, recover, word_emb, cf, x);
  k_wih   <<<2048,256, 0, stream>>>(x, wWih_f, wb_f, wWih_b, wb_b, gx);
  k_wlstm <<<128, 128, 0, stream>>>(gx, wWhh_f, wWhh_b, hseq);
  k_em    <<<2048,256, 0, stream>>>(hseq, W_tag, b_tag, em);
  k_crf   <<<64,  64,  0, stream>>>(em, tagp, trans, startv, endv, part);
  k_red   <<<1,   64,  0, stream>>>(part, out);
}

// Round 8
// 618.394 us; speedup vs baseline: 1.0278x; 1.0278x over previous
//
#include <hip/hip_runtime.h>
#include <hip/hip_bf16.h>
#include <hip/hip_fp16.h>

// Problem constants
#define NB 64
#define NT 256
#define TC 16
#define NL 25
#define NWORDS 16384   // NB*NT
#define DWd 150        // word-LSTM input dim
#define WEd 100
#define WPB 5          // words per k_char block

typedef _Float16 h2_t __attribute__((ext_vector_type(2)));

__device__ __forceinline__ float sigf(float x){ return __fdividef(1.f, 1.f + __expf(-x)); }
__device__ __forceinline__ float tanhf_(float x){
    float ax = fabsf(x);
    float e = __expf(-2.f*ax);                 // e in (0,1], overflow-safe
    float r = (1.f - e) * __fdividef(1.f, 1.f + e);
    return copysignf(r, x);
}

#if __has_builtin(__builtin_amdgcn_fdot2)
__device__ __forceinline__ float fdot2_(h2_t a, h2_t b, float c){
  return __builtin_amdgcn_fdot2(a, b, c, false);
}
#else
__device__ __forceinline__ float fdot2_(h2_t a, h2_t b, float c){
  return c + (float)a.x*(float)b.x + (float)a.y*(float)b.y;
}
#endif

// ---------------- Kernel 0: gxc[(c,d)][col] = cb_d[col] + sum_k char_emb[c][k]*cWih_d[k*100+col]
__global__ void k_gxc(const float* __restrict__ char_emb,
                      const float* __restrict__ cWih_f, const float* __restrict__ cb_f,
                      const float* __restrict__ cWih_b, const float* __restrict__ cb_b,
                      float* __restrict__ gxc){
  int i = blockIdx.x*blockDim.x + threadIdx.x;
  if (i >= 128*2*100) return;
  int col = i % 100; int d = (i/100) & 1; int c = i/200;
  const float* Wih = d ? cWih_b : cWih_f;
  const float* bb  = d ? cb_b  : cb_f;
  float acc = bb[col];
  #pragma unroll
  for (int k=0;k<25;k++) acc += char_emb[c*25+k]*Wih[k*100+col];
  gxc[i] = acc;
}

// ---------------- Kernel 1: char BiLSTM, thread = (word_in_block, gate_col).
__global__ __launch_bounds__(512) void k_char(const int* __restrict__ char_tensor,
   const int* __restrict__ char_lengths,
   const float* __restrict__ cWhh_f, const float* __restrict__ cWhh_b,
   const float* __restrict__ gxc, float* __restrict__ cf){
  __shared__ float h_lds[WPB][28];    // rows padded to 28 (16B-aligned float4 reads)
  __shared__ float act[WPB][100];
  __shared__ int   chars[WPB][TC];
  __shared__ int   lens[WPB];
  int tid = threadIdx.x;
  int d  = blockIdx.x & 1;
  int wb = blockIdx.x >> 1;           // 0..3276
  int w0 = wb*WPB;
  if (tid < WPB*TC){
    int ww = w0 + tid/TC;
    int cw = ww < NWORDS ? ww : NWORDS-1;
    chars[tid/TC][tid%TC] = char_tensor[cw*TC + (tid%TC)];
  }
  if (tid < WPB){
    int ww = w0 + tid;
    lens[tid] = char_lengths[ww < NWORDS ? ww : NWORDS-1];
  }
  int wsub = tid/100;                 // 0..4 for tid<500
  int j    = tid - wsub*100;          // gate col 0..99
  bool gate_thr = tid < WPB*100;
  const float* Wh = d ? cWhh_b : cWhh_f;
  float wcol[25];
  if (gate_thr){
    #pragma unroll
    for (int k=0;k<25;k++) wcol[k] = Wh[k*100 + j];
  }
  if (gate_thr && j < 28) h_lds[wsub][j] = 0.f;
  float c_reg = 0.f, h_last = 0.f;
  __syncthreads();
  int len = gate_thr ? lens[wsub] : 1;
  bool isg = (j >= 50) && (j < 75);
  float g_all[TC];
  if (gate_thr){
    #pragma unroll
    for (int t=0;t<TC;t++){
      int ci = d ? (len-1-t) : t;
      if (ci < 0 || ci >= TC) ci = 0;
      int cidx = chars[wsub][ci];
      g_all[t] = gxc[(size_t)(cidx*2+d)*100 + j];
    }
  }
  for (int t=0;t<TC;t++){
    if (gate_thr){
      float a = g_all[t];
      const float4* h4 = (const float4*)h_lds[wsub];
      #pragma unroll
      for (int kq=0;kq<6;kq++){
        float4 hq = h4[kq];
        a += hq.x*wcol[4*kq] + hq.y*wcol[4*kq+1] + hq.z*wcol[4*kq+2] + hq.w*wcol[4*kq+3];
      }
      a += h_lds[wsub][24]*wcol[24];
      act[wsub][j] = isg ? tanhf_(a) : sigf(a);
    }
    __syncthreads();
    if (gate_thr && j < 25 && t < len){
      float si = act[wsub][j], sf = act[wsub][25+j], sg = act[wsub][50+j], so = act[wsub][75+j];
      c_reg = sf*c_reg + si*sg;
      float hv = so*tanhf_(c_reg);
      h_lds[wsub][j] = hv;
      h_last = hv;
    }
    __syncthreads();
  }
  if (gate_thr && j < 25){
    int w = w0 + wsub;
    if (w < NWORDS) cf[(size_t)w*56 + d*28 + j] = h_last;
  }
}

// ---------------- Kernel 2: x[p][150] = word_emb[tok[p]] ++ cf[recover[p]] (cf stride 56)
__global__ void k_buildx(const int* __restrict__ tok, const int* __restrict__ recover,
                         const float* __restrict__ word_emb, const float* __restrict__ cf,
                         float* __restrict__ x){
  long i = (long)blockIdx.x*blockDim.x + threadIdx.x;
  if (i >= (long)NWORDS*DWd) return;
  int p = (int)(i/DWd); int e = (int)(i - (long)p*DWd);
  float v;
  if (e < WEd) v = word_emb[(long)tok[p]*WEd + e];
  else {
    int cidx = e - WEd;           // 0..49
    int dd = cidx / 25; int uu = cidx - dd*25;
    v = cf[(size_t)recover[p]*56 + dd*28 + uu];
  }
  x[i] = v;
}

// ---------------- Kernel 3: gx[d][p][400] = wb_d + x[p] @ wWih_d (fp32 tiled, M=16384,N=800,K=150)
__global__ __launch_bounds__(256) void k_wih(const float* __restrict__ x,
    const float* __restrict__ Wf, const float* __restrict__ bf,
    const float* __restrict__ Wb, const float* __restrict__ bbias,
    float* __restrict__ gx){
  __shared__ float As[150][36];
  int tid = threadIdx.x;
  int m0 = (blockIdx.x>>2)*32;
  int nt = blockIdx.x & 3;
  int n0 = nt*256;
  for (int i=tid; i<32*150; i+=256){
    int r = i/150; int k = i - r*150;
    As[k][r] = x[(long)(m0+r)*150 + k];
  }
  __syncthreads();
  int tn = tid & 31; int tm = tid >> 5;
  int j0 = n0 + tn*8;
  bool colok = j0 < 800;
  int d = (j0 >= 400) ? 1 : 0;
  const float* W = d ? Wb : Wf;
  int jc = j0 - d*400;
  float acc[4][8];
  #pragma unroll
  for (int mi=0;mi<4;mi++)
    #pragma unroll
    for (int ni=0;ni<8;ni++) acc[mi][ni]=0.f;
  if (colok){
    for (int k=0;k<150;k++){
      float4 b0 = *(const float4*)&W[k*400 + jc];
      float4 b1 = *(const float4*)&W[k*400 + jc + 4];
      float4 a4 = *(const float4*)&As[k][tm*4];
      float av[4] = {a4.x,a4.y,a4.z,a4.w};
      float bv[8] = {b0.x,b0.y,b0.z,b0.w,b1.x,b1.y,b1.z,b1.w};
      #pragma unroll
      for (int mi=0;mi<4;mi++)
        #pragma unroll
        for (int ni=0;ni<8;ni++) acc[mi][ni] += av[mi]*bv[ni];
    }
    const float* bptr = d ? bbias : bf;
    float bias[8];
    #pragma unroll
    for (int ni=0;ni<8;ni++) bias[ni] = bptr[jc+ni];
    #pragma unroll
    for (int mi=0;mi<4;mi++){
      int p = m0 + tm*4 + mi;
      float* orow = gx + ((long)d*NWORDS + p)*400 + jc;
      #pragma unroll
      for (int ni=0;ni<8;ni++) orow[ni] = acc[mi][ni] + bias[ni];
    }
  }
}

// ---------------- Kernel 4: word LSTM recurrence v6.
// block = (seq, dir), 128 threads (2 waves). Thread u<100 owns unit u (all 4
// gates in-thread). Weights: 400 f16 = 200 VGPRs (staged via LDS, chunk-
// consumed h keeps total live regs ~250 -> pure arch VGPRs, no AGPR reads).
// h double-buffered f16 in LDS -> ONE barrier/step. gx prefetched 4 steps
// ahead in 4 named float4 slots (time loop unrolled x4 -> static indices).
__global__ __launch_bounds__(128, 1) void k_wlstm(const float* __restrict__ gx,
     const float* __restrict__ Whf, const float* __restrict__ Whb,
     float* __restrict__ hseq){
  __shared__ float wstage[8000];                 // 20 rows x 400 cols (32KB)
  __shared__ __align__(16) _Float16 h16[2][112];
  int tid = threadIdx.x;
  int s = blockIdx.x & 63; int d = blockIdx.x >> 6;
  const float* Wh = d ? Whb : Whf;
  bool uthr = tid < 100;
  h2_t wi[50], wf[50], wg[50], wo[50];
  #pragma unroll
  for (int ch=0; ch<5; ch++){                    // rows 20ch .. 20ch+19
    for (int i=tid; i<2000; i+=128)
      ((float4*)wstage)[i] = ((const float4*)(Wh + ch*8000))[i];
    __syncthreads();
    if (uthr){
      #pragma unroll
      for (int p=0;p<10;p++){                    // row pair (2p,2p+1)
        int k = ch*10 + p;
        wi[k] = (h2_t){(_Float16)wstage[(2*p)*400 + tid],       (_Float16)wstage[(2*p+1)*400 + tid]};
        wf[k] = (h2_t){(_Float16)wstage[(2*p)*400 + 100 + tid], (_Float16)wstage[(2*p+1)*400 + 100 + tid]};
        wg[k] = (h2_t){(_Float16)wstage[(2*p)*400 + 200 + tid], (_Float16)wstage[(2*p+1)*400 + 200 + tid]};
        wo[k] = (h2_t){(_Float16)wstage[(2*p)*400 + 300 + tid], (_Float16)wstage[(2*p+1)*400 + 300 + tid]};
      }
    }
    __syncthreads();
  }
  if (tid < 112){ h16[0][tid] = (_Float16)0.f; h16[1][tid] = (_Float16)0.f; }
  float c_reg = 0.f;
  const float* gxd = gx + ((long)d*NWORDS + (long)s*256)*400;
  long hbase = ((long)d*NWORDS + (long)s*256)*100 + tid;
  __syncthreads();

  float4 g0, g1, g2, g3;
#define LOADG(G, T) \
  if (uthr && (T) < 256){ int _tt = d ? (255-(T)) : (T); const float* _r = gxd + _tt*400 + tid; \
    G.x = _r[0]; G.y = _r[100]; G.z = _r[200]; G.w = _r[300]; }

  LOADG(g0, 0) LOADG(g1, 1) LOADG(g2, 2) LOADG(g3, 3)

#define STEP(G, T, TN) { \
    const int cur = (T) & 1, nxt = cur ^ 1; \
    float ai = G.x, af = G.y, ag = G.z, ao = G.w; \
    if (uthr){ \
      const float4* hb = (const float4*)h16[cur]; \
      _Pragma("unroll") \
      for (int q = 0; q < 12; q++){ \
        float4 hc = hb[q]; \
        h2_t h0 = ((h2_t*)&hc)[0], h1 = ((h2_t*)&hc)[1], h2 = ((h2_t*)&hc)[2], h3 = ((h2_t*)&hc)[3]; \
        ai = fdot2_(h0, wi[4*q],   ai); af = fdot2_(h0, wf[4*q],   af); \
        ag = fdot2_(h0, wg[4*q],   ag); ao = fdot2_(h0, wo[4*q],   ao); \
        ai = fdot2_(h1, wi[4*q+1], ai); af = fdot2_(h1, wf[4*q+1], af); \
        ag = fdot2_(h1, wg[4*q+1], ag); ao = fdot2_(h1, wo[4*q+1], ao); \
        ai = fdot2_(h2, wi[4*q+2], ai); af = fdot2_(h2, wf[4*q+2], af); \
        ag = fdot2_(h2, wg[4*q+2], ag); ao = fdot2_(h2, wo[4*q+2], ao); \
        ai = fdot2_(h3, wi[4*q+3], ai); af = fdot2_(h3, wf[4*q+3], af); \
        ag = fdot2_(h3, wg[4*q+3], ag); ao = fdot2_(h3, wo[4*q+3], ao); \
      } \
      float2 tl = *(const float2*)&h16[cur][96]; \
      h2_t t0 = ((h2_t*)&tl)[0], t1 = ((h2_t*)&tl)[1]; \
      ai = fdot2_(t0, wi[48], ai); af = fdot2_(t0, wf[48], af); \
      ag = fdot2_(t0, wg[48], ag); ao = fdot2_(t0, wo[48], ao); \
      ai = fdot2_(t1, wi[49], ai); af = fdot2_(t1, wf[49], af); \
      ag = fdot2_(t1, wg[49], ag); ao = fdot2_(t1, wo[49], ao); \
    } \
    LOADG(G, TN) \
    if (uthr){ \
      c_reg = sigf(af)*c_reg + sigf(ai)*tanhf_(ag); \
      float hv = sigf(ao)*tanhf_(c_reg); \
      h16[nxt][tid] = (_Float16)hv; \
      int _tc = d ? (255-(T)) : (T); \
      hseq[hbase + (long)_tc*100 - tid + tid] = hv; \
      hseq[((long)d*NWORDS + s*256 + _tc)*100 + tid] = hv; \
    } \
    __syncthreads(); \
  }

  for (int tb = 0; tb < 256; tb += 4){
    STEP(g0, tb+0, tb+4)
    STEP(g1, tb+1, tb+5)
    STEP(g2, tb+2, tb+6)
    STEP(g3, tb+3, tb+7)
  }
#undef STEP
#undef LOADG
}

// ---------------- Kernel 5: emissions em[p][25] = b_tag + concat(h_f,h_b)[p] @ W_tag
__global__ __launch_bounds__(256) void k_em(const float* __restrict__ hseq,
    const float* __restrict__ Wtag, const float* __restrict__ btag,
    float* __restrict__ em){
  __shared__ float hrow[8][200];
  __shared__ float Ws[5000];
  int tid = threadIdx.x;
  for (int i=tid;i<5000;i+=256) Ws[i] = Wtag[i];
  int p0 = blockIdx.x*8;
  for (int i=tid;i<8*200;i+=256){
    int r = i/200; int k = i - r*200;
    int p = p0+r;
    hrow[r][k] = (k<100) ? hseq[(long)p*100+k] : hseq[((long)NWORDS + p)*100 + (k-100)];
  }
  __syncthreads();
  int r = tid>>5; int c = tid&31;
  if (c<25){
    float acc = btag[c];
    for (int k=0;k<200;k++) acc += hrow[r][k]*Ws[k*25+c];
    em[(long)(p0+r)*25 + c] = acc;
  }
}

// ---------------- Kernel 6: CRF per sequence: part[s] = logZ - gold.
__global__ __launch_bounds__(64) void k_crf(const float* __restrict__ em,
    const int* __restrict__ tag, const float* __restrict__ trans,
    const float* __restrict__ start, const float* __restrict__ endv,
    float* __restrict__ part){
  int s = blockIdx.x;
  int lane = threadIdx.x;
  int j = lane & 31; int kg = lane >> 5;
  int k0 = kg ? 13 : 0; int kcnt = kg ? 12 : 13;
  const float* emb = em + (long)s*256*25;
  float tr[13];
  #pragma unroll
  for (int kk=0;kk<13;kk++){
    int k = k0+kk;
    tr[kk] = (k<25 && j<25) ? trans[k*25+j] : 0.f;
  }
  float alpha = (j<25) ? (start[j] + emb[j]) : -1e30f;
  float enext = (j<25) ? emb[25 + j] : 0.f;
  for (int t=1;t<256;t++){
    float ecur = enext;
    if (t<255 && j<25) enext = emb[(t+1)*25 + j];
    float m = -1e30f;
    #pragma unroll
    for (int kk=0;kk<13;kk++){
      if (kk<kcnt){
        float a = __shfl(alpha, k0+kk, 64);
        m = fmaxf(m, a + tr[kk]);
      }
    }
    m = fmaxf(m, __shfl_xor(m, 32, 64));
    float ssum = 0.f;
    #pragma unroll
    for (int kk=0;kk<13;kk++){
      if (kk<kcnt){
        float a = __shfl(alpha, k0+kk, 64);
        ssum += __expf(a + tr[kk] - m);
      }
    }
    ssum += __shfl_xor(ssum, 32, 64);
    float anew = __logf(ssum) + m + ecur;
    alpha = (j<25) ? anew : -1e30f;
  }
  float val = (j<25 && kg==0) ? (alpha + endv[j]) : -1e30f;
  float m2 = -1e30f;
  for (int k=0;k<25;k++) m2 = fmaxf(m2, __shfl(val, k, 64));
  float s2 = 0.f;
  for (int k=0;k<25;k++) s2 += __expf(__shfl(val, k, 64) - m2);
  float logZ = __logf(s2) + m2;
  const int* tg = tag + s*256;
  float gp = 0.f;
  for (int t=lane; t<256; t+=64){
    int a = tg[t];
    gp += emb[t*25 + a];
    if (t<255) gp += trans[a*25 + tg[t+1]];
  }
  #pragma unroll
  for (int off=32; off; off>>=1) gp += __shfl_xor(gp, off, 64);
  if (lane==0){
    float gold = gp + start[tg[0]] + endv[tg[255]];
    part[s] = logZ - gold;
  }
}

// ---------------- Kernel 7: final reduce
__global__ __launch_bounds__(64) void k_red(const float* __restrict__ part, float* __restrict__ out){
  float v = part[threadIdx.x];
  #pragma unroll
  for (int off=32; off; off>>=1) v += __shfl_xor(v, off, 64);
  if (threadIdx.x==0) out[0] = v;
}

extern "C" void kernel_launch(void* const* d_in, const int* in_sizes, int n_in,
                              void* d_out, int out_size, void* d_ws, size_t ws_size,
                              hipStream_t stream){
  const int* tok          = (const int*)d_in[0];
  const int* tagp         = (const int*)d_in[1];
  const int* char_tensor  = (const int*)d_in[3];
  const int* char_lengths = (const int*)d_in[4];
  const int* recover      = (const int*)d_in[5];
  const float* word_emb = (const float*)d_in[6];
  const float* char_emb = (const float*)d_in[7];
  const float* cWih_f=(const float*)d_in[8];  const float* cWhh_f=(const float*)d_in[9];  const float* cb_f=(const float*)d_in[10];
  const float* cWih_b=(const float*)d_in[11]; const float* cWhh_b=(const float*)d_in[12]; const float* cb_b=(const float*)d_in[13];
  const float* wWih_f=(const float*)d_in[14]; const float* wWhh_f=(const float*)d_in[15]; const float* wb_f=(const float*)d_in[16];
  const float* wWih_b=(const float*)d_in[17]; const float* wWhh_b=(const float*)d_in[18]; const float* wb_b=(const float*)d_in[19];
  const float* W_tag=(const float*)d_in[20];  const float* b_tag=(const float*)d_in[21];
  const float* trans=(const float*)d_in[22];  const float* startv=(const float*)d_in[23]; const float* endv=(const float*)d_in[24];

  float* ws  = (float*)d_ws;
  float* gxc = ws;                 // 25600
  float* cf  = ws + 25600;         // 16384*56 = 917504
  float* x   = ws + 943104;        // 2457600
  float* gx  = ws + 3400704;       // 13107200
  float* hseq= ws + 16507904;      // 3276800
  float* em  = ws + 943104;        // overlays x (dead after k_wih), 409600
  float* part= ws + 19784704;      // 64   (high water ~79.1 MB)
  float* out = (float*)d_out;

  k_gxc   <<<100, 256, 0, stream>>>(char_emb, cWih_f, cb_f, cWih_b, cb_b, gxc);
  k_char  <<<6554,512, 0, stream>>>(char_tensor, char_lengths, cWhh_f, cWhh_b, gxc, cf);
  k_buildx<<<9600,256, 0, stream>>>(tok, recover, word_emb, cf, x);
  k_wih   <<<2048,256, 0, stream>>>(x, wWih_f, wb_f, wWih_b, wb_b, gx);
  k_wlstm <<<128, 128, 0, stream>>>(gx, wWhh_f, wWhh_b, hseq);
  k_em    <<<2048,256, 0, stream>>>(hseq, W_tag, b_tag, em);
  k_crf   <<<64,  64,  0, stream>>>(em, tagp, trans, startv, endv, part);
  k_red   <<<1,   64,  0, stream>>>(part, out);
}